// Round 5
// baseline (547.943 us; speedup 1.0000x reference)
//
#include <hip/hip_runtime.h>
#include <hip/hip_bf16.h>

// ComplexAttention: B=2, L=2048, D=1024, H=16, HD=64, SCALE=0.125
// Pipeline: pack(x,w) -> bf16 GEMM BK=64 (QKV, Q pre-scaled by SCALE*log2e, V stored transposed)
//           -> barrier-free flash attn (per-wave paired q-tiles, fixed-max exp2 softmax,
//              all MFMA frags gathered from global/L1, ones-frag l) -> bf16 GEMM (+bias, fp32 out)

using f32x4  = __attribute__((ext_vector_type(4))) float;
using short8 = __attribute__((ext_vector_type(8))) short;   // 8 bf16 = 4 VGPRs (MFMA A/B frag)
using bf16_t = __hip_bfloat16;

#define AS1 __attribute__((address_space(1)))
#define AS3 __attribute__((address_space(3)))

__device__ __forceinline__ void gload_lds16(const bf16_t* g, bf16_t* l) {
  __builtin_amdgcn_global_load_lds((const AS1 unsigned int*)g, (AS3 unsigned int*)l, 16, 0, 0);
}

__device__ __forceinline__ unsigned short bfbits(float f) {
  union { bf16_t h; unsigned short u; } c; c.h = __float2bfloat16(f); return c.u;
}

// ---------------------------------------------------------------- pack kernels
__global__ void pack_x_k(const float* __restrict__ xr, const float* __restrict__ xi,
                         bf16_t* __restrict__ out) {
  const int total4 = 4096 * 2048 / 4;
  for (int idx = blockIdx.x * blockDim.x + threadIdx.x; idx < total4;
       idx += gridDim.x * blockDim.x) {
    int m = idx >> 9, k = (idx & 511) * 4;
    const float* src = (k < 1024) ? (xr + (size_t)m * 1024 + k)
                                  : (xi + (size_t)m * 1024 + (k - 1024));
    float4 v = *(const float4*)src;
    unsigned int lo = (unsigned)bfbits(v.x) | ((unsigned)bfbits(v.y) << 16);
    unsigned int hi = (unsigned)bfbits(v.z) | ((unsigned)bfbits(v.w) << 16);
    *(uint2*)(out + (size_t)idx * 4) = make_uint2(lo, hi);
  }
}

__global__ void pack_wqkv_k(const float* __restrict__ wqr, const float* __restrict__ wqi,
                            const float* __restrict__ wkr, const float* __restrict__ wki,
                            const float* __restrict__ wvr, const float* __restrict__ wvi,
                            bf16_t* __restrict__ out) {
  const int total4 = 6144 * 2048 / 4;
  for (int idx = blockIdx.x * blockDim.x + threadIdx.x; idx < total4;
       idx += gridDim.x * blockDim.x) {
    int row = idx >> 9, k = (idx & 511) * 4;
    int sec = row >> 10, r1 = row & 1023;
    bool lowk = (k < 1024);
    int kk = lowk ? k : (k - 1024);
    const float* base = wqr; float sg = 1.f;
    switch (sec) {
      case 0: base = lowk ? wqr : wqi; sg = lowk ? 1.f : -1.f; break;
      case 1: base = lowk ? wqi : wqr; break;
      case 2: base = lowk ? wkr : wki; sg = lowk ? 1.f : -1.f; break;
      case 3: base = lowk ? wki : wkr; break;
      case 4: base = lowk ? wvr : wvi; sg = lowk ? 1.f : -1.f; break;
      case 5: base = lowk ? wvi : wvr; break;
    }
    float4 v = *(const float4*)(base + (size_t)r1 * 1024 + kk);
    unsigned int lo = (unsigned)bfbits(v.x * sg) | ((unsigned)bfbits(v.y * sg) << 16);
    unsigned int hi = (unsigned)bfbits(v.z * sg) | ((unsigned)bfbits(v.w * sg) << 16);
    *(uint2*)(out + (size_t)idx * 4) = make_uint2(lo, hi);
  }
}

__global__ void pack_wo_k(const float* __restrict__ wor, const float* __restrict__ woi,
                          bf16_t* __restrict__ out) {
  const int total4 = 2048 * 2048 / 4;
  for (int idx = blockIdx.x * blockDim.x + threadIdx.x; idx < total4;
       idx += gridDim.x * blockDim.x) {
    int row = idx >> 9, k = (idx & 511) * 4;
    int sec = row >> 10, r1 = row & 1023;
    bool lowk = (k < 1024);
    int kk = lowk ? k : (k - 1024);
    const float* base; float sg = 1.f;
    if (sec == 0) { base = lowk ? wor : woi; sg = lowk ? 1.f : -1.f; }
    else          { base = lowk ? woi : wor; }
    float4 v = *(const float4*)(base + (size_t)r1 * 1024 + kk);
    unsigned int lo = (unsigned)bfbits(v.x * sg) | ((unsigned)bfbits(v.y * sg) << 16);
    unsigned int hi = (unsigned)bfbits(v.z * sg) | ((unsigned)bfbits(v.w * sg) << 16);
    *(uint2*)(out + (size_t)idx * 4) = make_uint2(lo, hi);
  }
}

// ---------------------------------------------------------------- GEMM core (R3: BK=64 + swizzle)
// C[m,n] = sum_k A[m,k]*W[n,k]; A: Mx2048, W: Nx2048 bf16 row-major. 128x128 tile.
// LDS row = 64 elem (8 chunks of 16 B); LDS[r][c'] holds global chunk c'^(r&7).
__device__ __forceinline__ void gemm_core(const bf16_t* __restrict__ A,
                                          const bf16_t* __restrict__ W,
                                          int m0, int n0, f32x4 (&acc)[4][4]) {
  __shared__ __align__(16) bf16_t sA[128 * 64];
  __shared__ __align__(16) bf16_t sB[128 * 64];
  const int tid = threadIdx.x;
  const int lane = tid & 63, w = tid >> 6;
  const int wr = w >> 1, wc = w & 1;
  const int quad = lane >> 4, m16 = lane & 15;
  const int srow = w * 32 + (lane >> 3);                 // + i*8
  const int gcol = (((lane & 7) ^ (lane >> 3)) * 8);     // swizzled global k-offset
  const int swz7 = m16 & 7;                              // frag-read swizzle
  for (int k0 = 0; k0 < 2048; k0 += 64) {
    __syncthreads();
#pragma unroll
    for (int i = 0; i < 4; ++i) {
      gload_lds16(A + (size_t)(m0 + srow + i * 8) * 2048 + k0 + gcol,
                  sA + (size_t)(w * 32 + i * 8) * 64 + lane * 8);
      gload_lds16(W + (size_t)(n0 + srow + i * 8) * 2048 + k0 + gcol,
                  sB + (size_t)(w * 32 + i * 8) * 64 + lane * 8);
    }
    __syncthreads();
#pragma unroll
    for (int kk = 0; kk < 2; ++kk) {
      short8 af[4], bf[4];
#pragma unroll
      for (int i = 0; i < 4; ++i)
        af[i] = *(const short8*)(sA + (wr * 64 + i * 16 + m16) * 64 +
                                 ((kk * 4 + quad) ^ swz7) * 8);
#pragma unroll
      for (int j = 0; j < 4; ++j)
        bf[j] = *(const short8*)(sB + (wc * 64 + j * 16 + m16) * 64 +
                                 ((kk * 4 + quad) ^ swz7) * 8);
#pragma unroll
      for (int i = 0; i < 4; ++i)
#pragma unroll
        for (int j = 0; j < 4; ++j)
          acc[i][j] = __builtin_amdgcn_mfma_f32_16x16x32_bf16(af[i], bf[j], acc[i][j], 0, 0, 0);
    }
  }
}

// QKV GEMM: N=6144. cols 0..4095 -> qk [4096][4096] (Qr|Qi|Kr|Ki), Q pre-scaled by SCALE*log2e.
// cols 4096..6143 -> V transposed: vt[b*2048 + h*128 + ri*64 + d][seq]
__global__ __launch_bounds__(256) void gemm_qkv_k(const bf16_t* __restrict__ A,
                                                  const bf16_t* __restrict__ W,
                                                  bf16_t* __restrict__ qk,
                                                  bf16_t* __restrict__ vt) {
  f32x4 acc[4][4] = {};
  const int m0 = blockIdx.x * 128, n0 = blockIdx.y * 128;
  gemm_core(A, W, m0, n0, acc);
  const int lane = threadIdx.x & 63, w = threadIdx.x >> 6;
  const int wr = w >> 1, wc = w & 1, quad = lane >> 4, m16 = lane & 15;
#pragma unroll
  for (int i = 0; i < 4; ++i) {
    const int rowb = m0 + wr * 64 + i * 16 + quad * 4;  // C/D row = quad*4 + reg
#pragma unroll
    for (int j = 0; j < 4; ++j) {
      const int col = n0 + wc * 64 + j * 16 + m16;      // C/D col = lane&15
      if (col < 4096) {
        // 0.125 * log2(e): softmax later uses exp2
        const float sc = (col < 2048) ? 0.18033688f : 1.f;
#pragma unroll
        for (int r = 0; r < 4; ++r)
          qk[(size_t)(rowb + r) * 4096 + col] = __float2bfloat16(acc[i][j][r] * sc);
      } else {
        const int vcol = col - 4096;
        const int ri = vcol >> 10, dfeat = vcol & 1023;
        const int b = rowb >> 11, seq = rowb & 2047;
        const size_t vrow = (size_t)(b * 2048 + (dfeat >> 6) * 128 + ri * 64 + (dfeat & 63));
        unsigned int lo = (unsigned)bfbits(acc[i][j][0]) | ((unsigned)bfbits(acc[i][j][1]) << 16);
        unsigned int hi = (unsigned)bfbits(acc[i][j][2]) | ((unsigned)bfbits(acc[i][j][3]) << 16);
        *(uint2*)(vt + vrow * 2048 + seq) = make_uint2(lo, hi);
      }
    }
  }
}

// Output GEMM: N=2048 ([yr|yi]), fp32 out + bias.
__global__ __launch_bounds__(256) void gemm_out_k(const bf16_t* __restrict__ A,
                                                  const bf16_t* __restrict__ W,
                                                  const float* __restrict__ bor,
                                                  const float* __restrict__ boi,
                                                  float* __restrict__ out) {
  f32x4 acc[4][4] = {};
  const int m0 = blockIdx.x * 128, n0 = blockIdx.y * 128;
  gemm_core(A, W, m0, n0, acc);
  const int lane = threadIdx.x & 63, w = threadIdx.x >> 6;
  const int wr = w >> 1, wc = w & 1, quad = lane >> 4, m16 = lane & 15;
#pragma unroll
  for (int i = 0; i < 4; ++i) {
    const int rowb = m0 + wr * 64 + i * 16 + quad * 4;
#pragma unroll
    for (int j = 0; j < 4; ++j) {
      const int col = n0 + wc * 64 + j * 16 + m16;
      float bias; float* op;
      if (col < 1024) { bias = bor[col]; op = out + col; }
      else            { bias = boi[col - 1024]; op = out + 4194304 + (col - 1024); }
#pragma unroll
      for (int r = 0; r < 4; ++r)
        op[(size_t)(rowb + r) * 1024] = acc[i][j][r] + bias;
    }
  }
}

// ---------------------------------------------------------------- flash attention v4 (barrier-free)
// grid (16, B*H), 256 threads. Wave w of block g owns q-tile pair p = g*4+w:
// part A = rows [p*16, +16), part B = rows [(127-p)*16, +16). nT = 32-g (uniform per block).
// Per k-tile (64): S-frags (Q from regs, K gathered from qk/L1), exp2 fixed-max softmax,
// P via per-wave sP LDS round-trip (lgkm-only, no barriers), PV with V-frags gathered from
// vt/L1; l accumulated by a constant ones B-frag (lane m16==0). No __syncthreads anywhere.
__global__ __launch_bounds__(256, 3) void attn_k(const bf16_t* __restrict__ qk,
                                                 const bf16_t* __restrict__ vt,
                                                 bf16_t* __restrict__ acat) {
  __shared__ __align__(16) bf16_t sP[4][2][16 * 72];  // [wave][part], row stride 72
  const int tid = threadIdx.x, lane = tid & 63, w = tid >> 6;
  const int quad = lane >> 4, m16 = lane & 15;
  const int g = blockIdx.x, bh = blockIdx.y, b = bh >> 4, h = bh & 15;
  const int p = g * 4 + w;                       // pair index 0..63
  const size_t qkrow0 = (size_t)b * 2048;
  const int qA = p * 16, qB = (127 - p) * 16;
  const int nT = 32 - g;

  // Q fragments (A-operand: m=lane&15, k=quad*8+j), d-chunks of 32 over Dc=128 (Qr|Qi)
  short8 qfA[4], qfB[4];
  {
    const bf16_t* qa = qk + (qkrow0 + qA + m16) * 4096;
    const bf16_t* qb = qk + (qkrow0 + qB + m16) * 4096;
#pragma unroll
    for (int kk = 0; kk < 4; ++kk) {
      const int col = (kk >> 1) * 1024 + h * 64 + (kk & 1) * 32 + quad * 8;
      qfA[kk] = *(const short8*)(qa + col);
      qfB[kk] = *(const short8*)(qb + col);
    }
  }
  // constant ones B-frag: B[k][n]=1 iff n==0 -> column 0 of PV-extra = row-sum l
  short8 vones;
  {
    const short v = (m16 == 0) ? (short)0x3F80 : (short)0;
#pragma unroll
    for (int e = 0; e < 8; ++e) vones[e] = v;
  }
  f32x4 oA[9], oB[9];
#pragma unroll
  for (int j = 0; j < 9; ++j) { oA[j] = (f32x4){0.f,0.f,0.f,0.f}; oB[j] = (f32x4){0.f,0.f,0.f,0.f}; }

  const int qrowA = qA + quad * 4, qrowB = qB + quad * 4;
  const bf16_t* kb = qk + (qkrow0 + m16) * 4096 + 2048 + h * 64 + quad * 8;  // + row*4096
  const bf16_t* vb = vt + ((size_t)bh * 128 + m16) * 2048 + quad * 8;        // + d16*16*2048 + k
  bf16_t* pwA = &sP[w][0][0];
  bf16_t* pwB = &sP[w][1][0];

  for (int t = 0; t < nT; ++t) {
    const int k0 = t * 64;
    const bool withA = (t <= g);
    const bool dgA = (t == g), dgB = (t == nT - 1);

    // ---- S = Qs·K^T (K-frags gathered from global; shared between parts), exp2 per jt
#pragma unroll
    for (int jt = 0; jt < 4; ++jt) {
      const bf16_t* kr = kb + (size_t)(k0 + jt * 16) * 4096;
      short8 kf0 = *(const short8*)(kr);
      short8 kf1 = *(const short8*)(kr + 32);
      short8 kf2 = *(const short8*)(kr + 1024);
      short8 kf3 = *(const short8*)(kr + 1024 + 32);
      f32x4 aB = (f32x4){0.f,0.f,0.f,0.f};
      aB = __builtin_amdgcn_mfma_f32_16x16x32_bf16(qfB[0], kf0, aB, 0, 0, 0);
      aB = __builtin_amdgcn_mfma_f32_16x16x32_bf16(qfB[1], kf1, aB, 0, 0, 0);
      aB = __builtin_amdgcn_mfma_f32_16x16x32_bf16(qfB[2], kf2, aB, 0, 0, 0);
      aB = __builtin_amdgcn_mfma_f32_16x16x32_bf16(qfB[3], kf3, aB, 0, 0, 0);
#pragma unroll
      for (int r = 0; r < 4; ++r) {
        float s = aB[r];
        if (dgB && (k0 + jt * 16 + m16 > qrowB + r)) s = -1e30f;
        pwB[(quad * 4 + r) * 72 + jt * 16 + m16] =
            __float2bfloat16(__builtin_amdgcn_exp2f(s));
      }
      if (withA) {
        f32x4 aA = (f32x4){0.f,0.f,0.f,0.f};
        aA = __builtin_amdgcn_mfma_f32_16x16x32_bf16(qfA[0], kf0, aA, 0, 0, 0);
        aA = __builtin_amdgcn_mfma_f32_16x16x32_bf16(qfA[1], kf1, aA, 0, 0, 0);
        aA = __builtin_amdgcn_mfma_f32_16x16x32_bf16(qfA[2], kf2, aA, 0, 0, 0);
        aA = __builtin_amdgcn_mfma_f32_16x16x32_bf16(qfA[3], kf3, aA, 0, 0, 0);
#pragma unroll
        for (int r = 0; r < 4; ++r) {
          float s = aA[r];
          if (dgA && (k0 + jt * 16 + m16 > qrowA + r)) s = -1e30f;
          pwA[(quad * 4 + r) * 72 + jt * 16 + m16] =
              __float2bfloat16(__builtin_amdgcn_exp2f(s));
        }
      }
    }
    asm volatile("s_waitcnt lgkmcnt(0)" ::: "memory");  // own-wave P write->read

    // ---- O += P·V (V-frags gathered from global; shared between parts); j=8 ones -> l
#pragma unroll
    for (int kc = 0; kc < 2; ++kc) {
      short8 pB = *(const short8*)(pwB + m16 * 72 + kc * 32 + quad * 8);
      short8 pA;
      if (withA) pA = *(const short8*)(pwA + m16 * 72 + kc * 32 + quad * 8);
#pragma unroll
      for (int j = 0; j < 8; ++j) {
        short8 vf = *(const short8*)(vb + (size_t)(j * 16) * 2048 + k0 + kc * 32);
        oB[j] = __builtin_amdgcn_mfma_f32_16x16x32_bf16(pB, vf, oB[j], 0, 0, 0);
        if (withA) oA[j] = __builtin_amdgcn_mfma_f32_16x16x32_bf16(pA, vf, oA[j], 0, 0, 0);
      }
      oB[8] = __builtin_amdgcn_mfma_f32_16x16x32_bf16(pB, vones, oB[8], 0, 0, 0);
      if (withA) oA[8] = __builtin_amdgcn_mfma_f32_16x16x32_bf16(pA, vones, oA[8], 0, 0, 0);
    }
  }

  // ---- epilogue: l broadcast from lane (quad*16), normalize, write [B,L,2048]=[out_r|out_i]
#pragma unroll
  for (int part = 0; part < 2; ++part) {
    f32x4* o = part ? oB : oA;
    const int qrow = part ? qrowB : qrowA;
    float inv[4];
#pragma unroll
    for (int r = 0; r < 4; ++r)
      inv[r] = 1.f / __shfl(o[8][r], lane & 48);
#pragma unroll
    for (int j = 0; j < 8; ++j) {
      const int d = j * 16 + m16;
      const int col = (d < 64) ? (h * 64 + d) : (1024 + h * 64 + (d - 64));
#pragma unroll
      for (int r = 0; r < 4; ++r)
        acat[((size_t)b * 2048 + qrow + r) * 2048 + col] = __float2bfloat16(o[j][r] * inv[r]);
    }
  }
}

// ---------------------------------------------------------------- launch
extern "C" void kernel_launch(void* const* d_in, const int* in_sizes, int n_in,
                              void* d_out, int out_size, void* d_ws, size_t ws_size,
                              hipStream_t stream) {
  const float* xr  = (const float*)d_in[0];
  const float* xi  = (const float*)d_in[1];
  const float* wqr = (const float*)d_in[2];
  const float* wqi = (const float*)d_in[3];
  const float* wkr = (const float*)d_in[4];
  const float* wki = (const float*)d_in[5];
  const float* wvr = (const float*)d_in[6];
  const float* wvi = (const float*)d_in[7];
  const float* wor = (const float*)d_in[8];
  const float* woi = (const float*)d_in[9];
  const float* bor = (const float*)d_in[10];
  const float* boi = (const float*)d_in[11];
  float* out = (float*)d_out;

  char* ws = (char*)d_ws;
  bf16_t* Xcat = (bf16_t*)(ws);                   // 4096x2048   16 MB
  bf16_t* Wqkv = (bf16_t*)(ws + 16777216ull);     // 6144x2048   24 MB
  bf16_t* QKb  = (bf16_t*)(ws + 41943040ull);     // 4096x4096   32 MB
  bf16_t* Vt   = (bf16_t*)(ws + 75497472ull);     // 4096x2048   16 MB (V transposed)
  bf16_t* Acat = (bf16_t*)(ws + 92274688ull);     // 4096x2048   16 MB
  bf16_t* Wo   = (bf16_t*)(ws + 109051904ull);    // 2048x2048    8 MB

  pack_x_k<<<2048, 256, 0, stream>>>(xr, xi, Xcat);
  pack_wqkv_k<<<2048, 256, 0, stream>>>(wqr, wqi, wkr, wki, wvr, wvi, Wqkv);
  pack_wo_k<<<1024, 256, 0, stream>>>(wor, woi, Wo);
  gemm_qkv_k<<<dim3(32, 48), 256, 0, stream>>>(Xcat, Wqkv, QKb, Vt);
  attn_k<<<dim3(16, 32), 256, 0, stream>>>(QKb, Vt, Acat);
  gemm_out_k<<<dim3(32, 16), 256, 0, stream>>>(Acat, Wo, bor, boi, out);
}

// Round 6
// 545.302 us; speedup vs baseline: 1.0048x; 1.0048x over previous
//
#include <hip/hip_runtime.h>
#include <hip/hip_bf16.h>

// ComplexAttention: B=2, L=2048, D=1024, H=16, HD=64, SCALE=0.125
// Pipeline: pack(x,w) -> bf16 GEMM BK=64 (QKV, Q pre-scaled by SCALE*log2e, V stored transposed)
//           -> flash attn (32-row paired q-tiles, 1024 blocks, 3 blocks/CU, fixed-max exp2
//              softmax, ones-frag l) -> bf16 GEMM (+bias, fp32 out)

using f32x4  = __attribute__((ext_vector_type(4))) float;
using short8 = __attribute__((ext_vector_type(8))) short;   // 8 bf16 = 4 VGPRs (MFMA A/B frag)
using bf16_t = __hip_bfloat16;

#define AS1 __attribute__((address_space(1)))
#define AS3 __attribute__((address_space(3)))

__device__ __forceinline__ void gload_lds16(const bf16_t* g, bf16_t* l) {
  __builtin_amdgcn_global_load_lds((const AS1 unsigned int*)g, (AS3 unsigned int*)l, 16, 0, 0);
}

__device__ __forceinline__ unsigned short bfbits(float f) {
  union { bf16_t h; unsigned short u; } c; c.h = __float2bfloat16(f); return c.u;
}

// ---------------------------------------------------------------- pack kernels
__global__ void pack_x_k(const float* __restrict__ xr, const float* __restrict__ xi,
                         bf16_t* __restrict__ out) {
  const int total4 = 4096 * 2048 / 4;
  for (int idx = blockIdx.x * blockDim.x + threadIdx.x; idx < total4;
       idx += gridDim.x * blockDim.x) {
    int m = idx >> 9, k = (idx & 511) * 4;
    const float* src = (k < 1024) ? (xr + (size_t)m * 1024 + k)
                                  : (xi + (size_t)m * 1024 + (k - 1024));
    float4 v = *(const float4*)src;
    unsigned int lo = (unsigned)bfbits(v.x) | ((unsigned)bfbits(v.y) << 16);
    unsigned int hi = (unsigned)bfbits(v.z) | ((unsigned)bfbits(v.w) << 16);
    *(uint2*)(out + (size_t)idx * 4) = make_uint2(lo, hi);
  }
}

__global__ void pack_wqkv_k(const float* __restrict__ wqr, const float* __restrict__ wqi,
                            const float* __restrict__ wkr, const float* __restrict__ wki,
                            const float* __restrict__ wvr, const float* __restrict__ wvi,
                            bf16_t* __restrict__ out) {
  const int total4 = 6144 * 2048 / 4;
  for (int idx = blockIdx.x * blockDim.x + threadIdx.x; idx < total4;
       idx += gridDim.x * blockDim.x) {
    int row = idx >> 9, k = (idx & 511) * 4;
    int sec = row >> 10, r1 = row & 1023;
    bool lowk = (k < 1024);
    int kk = lowk ? k : (k - 1024);
    const float* base = wqr; float sg = 1.f;
    switch (sec) {
      case 0: base = lowk ? wqr : wqi; sg = lowk ? 1.f : -1.f; break;
      case 1: base = lowk ? wqi : wqr; break;
      case 2: base = lowk ? wkr : wki; sg = lowk ? 1.f : -1.f; break;
      case 3: base = lowk ? wki : wkr; break;
      case 4: base = lowk ? wvr : wvi; sg = lowk ? 1.f : -1.f; break;
      case 5: base = lowk ? wvi : wvr; break;
    }
    float4 v = *(const float4*)(base + (size_t)r1 * 1024 + kk);
    unsigned int lo = (unsigned)bfbits(v.x * sg) | ((unsigned)bfbits(v.y * sg) << 16);
    unsigned int hi = (unsigned)bfbits(v.z * sg) | ((unsigned)bfbits(v.w * sg) << 16);
    *(uint2*)(out + (size_t)idx * 4) = make_uint2(lo, hi);
  }
}

__global__ void pack_wo_k(const float* __restrict__ wor, const float* __restrict__ woi,
                          bf16_t* __restrict__ out) {
  const int total4 = 2048 * 2048 / 4;
  for (int idx = blockIdx.x * blockDim.x + threadIdx.x; idx < total4;
       idx += gridDim.x * blockDim.x) {
    int row = idx >> 9, k = (idx & 511) * 4;
    int sec = row >> 10, r1 = row & 1023;
    bool lowk = (k < 1024);
    int kk = lowk ? k : (k - 1024);
    const float* base; float sg = 1.f;
    if (sec == 0) { base = lowk ? wor : woi; sg = lowk ? 1.f : -1.f; }
    else          { base = lowk ? woi : wor; }
    float4 v = *(const float4*)(base + (size_t)r1 * 1024 + kk);
    unsigned int lo = (unsigned)bfbits(v.x * sg) | ((unsigned)bfbits(v.y * sg) << 16);
    unsigned int hi = (unsigned)bfbits(v.z * sg) | ((unsigned)bfbits(v.w * sg) << 16);
    *(uint2*)(out + (size_t)idx * 4) = make_uint2(lo, hi);
  }
}

// ---------------------------------------------------------------- GEMM core (R3: BK=64 + swizzle)
// C[m,n] = sum_k A[m,k]*W[n,k]; A: Mx2048, W: Nx2048 bf16 row-major. 128x128 tile.
// LDS row = 64 elem (8 chunks of 16 B); LDS[r][c'] holds global chunk c'^(r&7).
__device__ __forceinline__ void gemm_core(const bf16_t* __restrict__ A,
                                          const bf16_t* __restrict__ W,
                                          int m0, int n0, f32x4 (&acc)[4][4]) {
  __shared__ __align__(16) bf16_t sA[128 * 64];
  __shared__ __align__(16) bf16_t sB[128 * 64];
  const int tid = threadIdx.x;
  const int lane = tid & 63, w = tid >> 6;
  const int wr = w >> 1, wc = w & 1;
  const int quad = lane >> 4, m16 = lane & 15;
  const int srow = w * 32 + (lane >> 3);                 // + i*8
  const int gcol = (((lane & 7) ^ (lane >> 3)) * 8);     // swizzled global k-offset
  const int swz7 = m16 & 7;                              // frag-read swizzle
  for (int k0 = 0; k0 < 2048; k0 += 64) {
    __syncthreads();
#pragma unroll
    for (int i = 0; i < 4; ++i) {
      gload_lds16(A + (size_t)(m0 + srow + i * 8) * 2048 + k0 + gcol,
                  sA + (size_t)(w * 32 + i * 8) * 64 + lane * 8);
      gload_lds16(W + (size_t)(n0 + srow + i * 8) * 2048 + k0 + gcol,
                  sB + (size_t)(w * 32 + i * 8) * 64 + lane * 8);
    }
    __syncthreads();
#pragma unroll
    for (int kk = 0; kk < 2; ++kk) {
      short8 af[4], bf[4];
#pragma unroll
      for (int i = 0; i < 4; ++i)
        af[i] = *(const short8*)(sA + (wr * 64 + i * 16 + m16) * 64 +
                                 ((kk * 4 + quad) ^ swz7) * 8);
#pragma unroll
      for (int j = 0; j < 4; ++j)
        bf[j] = *(const short8*)(sB + (wc * 64 + j * 16 + m16) * 64 +
                                 ((kk * 4 + quad) ^ swz7) * 8);
#pragma unroll
      for (int i = 0; i < 4; ++i)
#pragma unroll
        for (int j = 0; j < 4; ++j)
          acc[i][j] = __builtin_amdgcn_mfma_f32_16x16x32_bf16(af[i], bf[j], acc[i][j], 0, 0, 0);
    }
  }
}

// QKV GEMM: N=6144. cols 0..4095 -> qk [4096][4096] (Qr|Qi|Kr|Ki), Q pre-scaled by SCALE*log2e.
// cols 4096..6143 -> V transposed: vt[b*2048 + h*128 + ri*64 + d][seq]
__global__ __launch_bounds__(256) void gemm_qkv_k(const bf16_t* __restrict__ A,
                                                  const bf16_t* __restrict__ W,
                                                  bf16_t* __restrict__ qk,
                                                  bf16_t* __restrict__ vt) {
  f32x4 acc[4][4] = {};
  const int m0 = blockIdx.x * 128, n0 = blockIdx.y * 128;
  gemm_core(A, W, m0, n0, acc);
  const int lane = threadIdx.x & 63, w = threadIdx.x >> 6;
  const int wr = w >> 1, wc = w & 1, quad = lane >> 4, m16 = lane & 15;
#pragma unroll
  for (int i = 0; i < 4; ++i) {
    const int rowb = m0 + wr * 64 + i * 16 + quad * 4;  // C/D row = quad*4 + reg
#pragma unroll
    for (int j = 0; j < 4; ++j) {
      const int col = n0 + wc * 64 + j * 16 + m16;      // C/D col = lane&15
      if (col < 4096) {
        // 0.125 * log2(e): softmax later uses exp2
        const float sc = (col < 2048) ? 0.18033688f : 1.f;
#pragma unroll
        for (int r = 0; r < 4; ++r)
          qk[(size_t)(rowb + r) * 4096 + col] = __float2bfloat16(acc[i][j][r] * sc);
      } else {
        const int vcol = col - 4096;
        const int ri = vcol >> 10, dfeat = vcol & 1023;
        const int b = rowb >> 11, seq = rowb & 2047;
        const size_t vrow = (size_t)(b * 2048 + (dfeat >> 6) * 128 + ri * 64 + (dfeat & 63));
        unsigned int lo = (unsigned)bfbits(acc[i][j][0]) | ((unsigned)bfbits(acc[i][j][1]) << 16);
        unsigned int hi = (unsigned)bfbits(acc[i][j][2]) | ((unsigned)bfbits(acc[i][j][3]) << 16);
        *(uint2*)(vt + vrow * 2048 + seq) = make_uint2(lo, hi);
      }
    }
  }
}

// Output GEMM: N=2048 ([yr|yi]), fp32 out + bias.
__global__ __launch_bounds__(256) void gemm_out_k(const bf16_t* __restrict__ A,
                                                  const bf16_t* __restrict__ W,
                                                  const float* __restrict__ bor,
                                                  const float* __restrict__ boi,
                                                  float* __restrict__ out) {
  f32x4 acc[4][4] = {};
  const int m0 = blockIdx.x * 128, n0 = blockIdx.y * 128;
  gemm_core(A, W, m0, n0, acc);
  const int lane = threadIdx.x & 63, w = threadIdx.x >> 6;
  const int wr = w >> 1, wc = w & 1, quad = lane >> 4, m16 = lane & 15;
#pragma unroll
  for (int i = 0; i < 4; ++i) {
    const int rowb = m0 + wr * 64 + i * 16 + quad * 4;
#pragma unroll
    for (int j = 0; j < 4; ++j) {
      const int col = n0 + wc * 64 + j * 16 + m16;
      float bias; float* op;
      if (col < 1024) { bias = bor[col]; op = out + col; }
      else            { bias = boi[col - 1024]; op = out + 4194304 + (col - 1024); }
#pragma unroll
      for (int r = 0; r < 4; ++r)
        op[(size_t)(rowb + r) * 1024] = acc[i][j][r] + bias;
    }
  }
}

// ---------------------------------------------------------------- flash attention v5
// grid (32, B*H), 256 threads, 3 blocks/CU. Block x pairs 32-row q-tiles: part A = tile x
// (rows x*32..+32), part B = tile 63-x. Wave w owns A-slice (w&1) and B-slice (w>>1), 16
// rows each -> every wave does exactly (x>>1)+1 + nT = 33 part-tiles (uniform). K/V staged
// via global_load_lds + XOR chunk swizzle into shared LDS (BK=64); fixed-max exp2 softmax;
// l via constant ones B-frag. t_maxA = x>>1 and nT are wave-uniform (no divergence).
__global__ __launch_bounds__(256, 3) void attn_k(const bf16_t* __restrict__ qk,
                                                 const bf16_t* __restrict__ vt,
                                                 bf16_t* __restrict__ acat) {
  __shared__ __align__(16) bf16_t sK[64 * 128];       // 16 KB
  __shared__ __align__(16) bf16_t sV[128 * 64];       // 16 KB
  __shared__ __align__(16) bf16_t sP[4][2][16 * 72];  // 18 KB
  const int tid = threadIdx.x, lane = tid & 63, w = tid >> 6;
  const int quad = lane >> 4, m16 = lane & 15;
  const int x = blockIdx.x, bh = blockIdx.y, b = bh >> 4, h = bh & 15;
  const size_t qkrow0 = (size_t)b * 2048;
  const int qA = x * 32 + (w & 1) * 16;          // this wave's A rows
  const int qB = (63 - x) * 32 + (w >> 1) * 16;  // this wave's B rows
  const int tA = x >> 1;                         // last tile touching part A (wave-uniform)
  const int nT = ((2031 - 32 * x) >> 6) + 1;     // tiles for part B (wave-uniform)
  const int swz7 = m16 & 7;

  // Q fragments (A-operand: m=lane&15, k=quad*8+j), d-chunks of 32 over Dc=128 (Qr|Qi)
  short8 qfA[4], qfB[4];
  {
    const bf16_t* qa = qk + (qkrow0 + qA + m16) * 4096;
    const bf16_t* qb = qk + (qkrow0 + qB + m16) * 4096;
#pragma unroll
    for (int kk = 0; kk < 4; ++kk) {
      const int col = (kk >> 1) * 1024 + h * 64 + (kk & 1) * 32 + quad * 8;
      qfA[kk] = *(const short8*)(qa + col);
      qfB[kk] = *(const short8*)(qb + col);
    }
  }
  // constant ones B-frag: B[k][n]=1 iff n==0 -> PV col 0 = row-sum l
  short8 vones;
  {
    const short v = (m16 == 0) ? (short)0x3F80 : (short)0;
#pragma unroll
    for (int e = 0; e < 8; ++e) vones[e] = v;
  }
  f32x4 oA[9], oB[9];
#pragma unroll
  for (int j = 0; j < 9; ++j) { oA[j] = (f32x4){0.f,0.f,0.f,0.f}; oB[j] = (f32x4){0.f,0.f,0.f,0.f}; }

  const int qrowA = qA + quad * 4, qrowB = qB + quad * 4;
  bf16_t* pwA = &sP[w][0][0];
  bf16_t* pwB = &sP[w][1][0];

  // staging geometry (identical to R3)
  const int kl4 = lane >> 4, kl15 = lane & 15;   // K tile: 4 rows/instr (256 B rows)
  const int vl3 = lane >> 3;                     // V tile: 8 rows/instr (128 B rows)
  const int vg7 = ((lane & 7) ^ vl3) * 8;

  for (int t = 0; t < nT; ++t) {
    const int k0 = t * 64;
    __syncthreads();
    // stage K: 64 rows x 128 elem (Kr|Ki of head h); row&7 = (i*4 + lane>>4)&7
#pragma unroll
    for (int i = 0; i < 4; ++i) {
      const int row = w * 16 + i * 4 + kl4;
      const int g = kl15 ^ (row & 7);            // low-3 XOR; bit3 of kl15 preserved
      const int col = 2048 + (g >> 3) * 1024 + h * 64 + (g & 7) * 8;
      gload_lds16(qk + (qkrow0 + k0 + row) * 4096 + col,
                  sK + (size_t)(w * 16 + i * 4) * 128 + lane * 8);
    }
    // stage V^T: 128 d-rows x 64 k; row&7 = lane>>3
#pragma unroll
    for (int i = 0; i < 4; ++i) {
      const int row = w * 32 + i * 8 + vl3;
      gload_lds16(vt + ((size_t)bh * 128 + row) * 2048 + k0 + vg7,
                  sV + (size_t)(w * 32 + i * 8) * 64 + lane * 8);
    }
    __syncthreads();

    const bool withA = (t <= tA);
    const bool dgA = (t == tA), dgB = (t == nT - 1);

    // ---- S = Qs·K^T; exp2 fixed-max softmax into per-wave sP
#pragma unroll
    for (int jt = 0; jt < 4; ++jt) {
      short8 kf[4];
#pragma unroll
      for (int kk = 0; kk < 4; ++kk)
        kf[kk] = *(const short8*)(sK + (jt * 16 + m16) * 128 + ((kk * 4 + quad) ^ swz7) * 8);
      f32x4 aB = (f32x4){0.f,0.f,0.f,0.f};
#pragma unroll
      for (int kk = 0; kk < 4; ++kk)
        aB = __builtin_amdgcn_mfma_f32_16x16x32_bf16(qfB[kk], kf[kk], aB, 0, 0, 0);
#pragma unroll
      for (int r = 0; r < 4; ++r) {
        float s = aB[r];
        if (dgB && (k0 + jt * 16 + m16 > qrowB + r)) s = -1e30f;
        pwB[(quad * 4 + r) * 72 + jt * 16 + m16] =
            __float2bfloat16(__builtin_amdgcn_exp2f(s));
      }
      if (withA) {
        f32x4 aA = (f32x4){0.f,0.f,0.f,0.f};
#pragma unroll
        for (int kk = 0; kk < 4; ++kk)
          aA = __builtin_amdgcn_mfma_f32_16x16x32_bf16(qfA[kk], kf[kk], aA, 0, 0, 0);
#pragma unroll
        for (int r = 0; r < 4; ++r) {
          float s = aA[r];
          if (dgA && (k0 + jt * 16 + m16 > qrowA + r)) s = -1e30f;
          pwA[(quad * 4 + r) * 72 + jt * 16 + m16] =
              __float2bfloat16(__builtin_amdgcn_exp2f(s));
        }
      }
    }
    asm volatile("s_waitcnt lgkmcnt(0)" ::: "memory");  // own-wave P write->read

    // ---- O += P·V (j=8 = ones-frag -> l); V frags shared between parts
#pragma unroll
    for (int kc = 0; kc < 2; ++kc) {
      short8 pB = *(const short8*)(pwB + m16 * 72 + kc * 32 + quad * 8);
      short8 pA;
      if (withA) pA = *(const short8*)(pwA + m16 * 72 + kc * 32 + quad * 8);
#pragma unroll
      for (int j = 0; j < 8; ++j) {
        short8 vf = *(const short8*)(sV + (j * 16 + m16) * 64 + ((kc * 4 + quad) ^ swz7) * 8);
        oB[j] = __builtin_amdgcn_mfma_f32_16x16x32_bf16(pB, vf, oB[j], 0, 0, 0);
        if (withA) oA[j] = __builtin_amdgcn_mfma_f32_16x16x32_bf16(pA, vf, oA[j], 0, 0, 0);
      }
      oB[8] = __builtin_amdgcn_mfma_f32_16x16x32_bf16(pB, vones, oB[8], 0, 0, 0);
      if (withA) oA[8] = __builtin_amdgcn_mfma_f32_16x16x32_bf16(pA, vones, oA[8], 0, 0, 0);
    }
  }

  // ---- epilogue: l broadcast from lane (quad*16), normalize, write [B,L,2048]=[out_r|out_i]
#pragma unroll
  for (int part = 0; part < 2; ++part) {
    f32x4* o = part ? oB : oA;
    const int qrow = part ? qrowB : qrowA;
    float inv[4];
#pragma unroll
    for (int r = 0; r < 4; ++r)
      inv[r] = 1.f / __shfl(o[8][r], lane & 48);
#pragma unroll
    for (int j = 0; j < 8; ++j) {
      const int d = j * 16 + m16;
      const int col = (d < 64) ? (h * 64 + d) : (1024 + h * 64 + (d - 64));
#pragma unroll
      for (int r = 0; r < 4; ++r)
        acat[((size_t)b * 2048 + qrow + r) * 2048 + col] = __float2bfloat16(o[j][r] * inv[r]);
    }
  }
}

// ---------------------------------------------------------------- launch
extern "C" void kernel_launch(void* const* d_in, const int* in_sizes, int n_in,
                              void* d_out, int out_size, void* d_ws, size_t ws_size,
                              hipStream_t stream) {
  const float* xr  = (const float*)d_in[0];
  const float* xi  = (const float*)d_in[1];
  const float* wqr = (const float*)d_in[2];
  const float* wqi = (const float*)d_in[3];
  const float* wkr = (const float*)d_in[4];
  const float* wki = (const float*)d_in[5];
  const float* wvr = (const float*)d_in[6];
  const float* wvi = (const float*)d_in[7];
  const float* wor = (const float*)d_in[8];
  const float* woi = (const float*)d_in[9];
  const float* bor = (const float*)d_in[10];
  const float* boi = (const float*)d_in[11];
  float* out = (float*)d_out;

  char* ws = (char*)d_ws;
  bf16_t* Xcat = (bf16_t*)(ws);                   // 4096x2048   16 MB
  bf16_t* Wqkv = (bf16_t*)(ws + 16777216ull);     // 6144x2048   24 MB
  bf16_t* QKb  = (bf16_t*)(ws + 41943040ull);     // 4096x4096   32 MB
  bf16_t* Vt   = (bf16_t*)(ws + 75497472ull);     // 4096x2048   16 MB (V transposed)
  bf16_t* Acat = (bf16_t*)(ws + 92274688ull);     // 4096x2048   16 MB
  bf16_t* Wo   = (bf16_t*)(ws + 109051904ull);    // 2048x2048    8 MB

  pack_x_k<<<2048, 256, 0, stream>>>(xr, xi, Xcat);
  pack_wqkv_k<<<2048, 256, 0, stream>>>(wqr, wqi, wkr, wki, wvr, wvi, Wqkv);
  pack_wo_k<<<1024, 256, 0, stream>>>(wor, woi, Wo);
  gemm_qkv_k<<<dim3(32, 48), 256, 0, stream>>>(Xcat, Wqkv, QKb, Vt);
  attn_k<<<dim3(32, 32), 256, 0, stream>>>(QKb, Vt, Acat);
  gemm_out_k<<<dim3(32, 16), 256, 0, stream>>>(Acat, Wo, bor, boi, out);
}

// Round 7
// 415.565 us; speedup vs baseline: 1.3185x; 1.3122x over previous
//
#include <hip/hip_runtime.h>
#include <hip/hip_bf16.h>

// ComplexAttention: B=2, L=2048, D=1024, H=16, HD=64, SCALE=0.125
// Pipeline: pack(x,w) -> bf16 GEMM BK=64 (QKV, Q pre-scaled by SCALE*log2e, V stored transposed)
//           -> flash attn (one 16-row slice per wave, paired 32-row q-tiles, 1024 blocks,
//              3 blocks/CU, fixed-max exp2 softmax, ones-frag l) -> bf16 GEMM (+bias, fp32 out)

using f32x4  = __attribute__((ext_vector_type(4))) float;
using short8 = __attribute__((ext_vector_type(8))) short;   // 8 bf16 = 4 VGPRs (MFMA A/B frag)
using bf16_t = __hip_bfloat16;

#define AS1 __attribute__((address_space(1)))
#define AS3 __attribute__((address_space(3)))

__device__ __forceinline__ void gload_lds16(const bf16_t* g, bf16_t* l) {
  __builtin_amdgcn_global_load_lds((const AS1 unsigned int*)g, (AS3 unsigned int*)l, 16, 0, 0);
}

__device__ __forceinline__ unsigned short bfbits(float f) {
  union { bf16_t h; unsigned short u; } c; c.h = __float2bfloat16(f); return c.u;
}

// ---------------------------------------------------------------- pack kernels
__global__ void pack_x_k(const float* __restrict__ xr, const float* __restrict__ xi,
                         bf16_t* __restrict__ out) {
  const int total4 = 4096 * 2048 / 4;
  for (int idx = blockIdx.x * blockDim.x + threadIdx.x; idx < total4;
       idx += gridDim.x * blockDim.x) {
    int m = idx >> 9, k = (idx & 511) * 4;
    const float* src = (k < 1024) ? (xr + (size_t)m * 1024 + k)
                                  : (xi + (size_t)m * 1024 + (k - 1024));
    float4 v = *(const float4*)src;
    unsigned int lo = (unsigned)bfbits(v.x) | ((unsigned)bfbits(v.y) << 16);
    unsigned int hi = (unsigned)bfbits(v.z) | ((unsigned)bfbits(v.w) << 16);
    *(uint2*)(out + (size_t)idx * 4) = make_uint2(lo, hi);
  }
}

__global__ void pack_wqkv_k(const float* __restrict__ wqr, const float* __restrict__ wqi,
                            const float* __restrict__ wkr, const float* __restrict__ wki,
                            const float* __restrict__ wvr, const float* __restrict__ wvi,
                            bf16_t* __restrict__ out) {
  const int total4 = 6144 * 2048 / 4;
  for (int idx = blockIdx.x * blockDim.x + threadIdx.x; idx < total4;
       idx += gridDim.x * blockDim.x) {
    int row = idx >> 9, k = (idx & 511) * 4;
    int sec = row >> 10, r1 = row & 1023;
    bool lowk = (k < 1024);
    int kk = lowk ? k : (k - 1024);
    const float* base = wqr; float sg = 1.f;
    switch (sec) {
      case 0: base = lowk ? wqr : wqi; sg = lowk ? 1.f : -1.f; break;
      case 1: base = lowk ? wqi : wqr; break;
      case 2: base = lowk ? wkr : wki; sg = lowk ? 1.f : -1.f; break;
      case 3: base = lowk ? wki : wkr; break;
      case 4: base = lowk ? wvr : wvi; sg = lowk ? 1.f : -1.f; break;
      case 5: base = lowk ? wvi : wvr; break;
    }
    float4 v = *(const float4*)(base + (size_t)r1 * 1024 + kk);
    unsigned int lo = (unsigned)bfbits(v.x * sg) | ((unsigned)bfbits(v.y * sg) << 16);
    unsigned int hi = (unsigned)bfbits(v.z * sg) | ((unsigned)bfbits(v.w * sg) << 16);
    *(uint2*)(out + (size_t)idx * 4) = make_uint2(lo, hi);
  }
}

__global__ void pack_wo_k(const float* __restrict__ wor, const float* __restrict__ woi,
                          bf16_t* __restrict__ out) {
  const int total4 = 2048 * 2048 / 4;
  for (int idx = blockIdx.x * blockDim.x + threadIdx.x; idx < total4;
       idx += gridDim.x * blockDim.x) {
    int row = idx >> 9, k = (idx & 511) * 4;
    int sec = row >> 10, r1 = row & 1023;
    bool lowk = (k < 1024);
    int kk = lowk ? k : (k - 1024);
    const float* base; float sg = 1.f;
    if (sec == 0) { base = lowk ? wor : woi; sg = lowk ? 1.f : -1.f; }
    else          { base = lowk ? woi : wor; }
    float4 v = *(const float4*)(base + (size_t)r1 * 1024 + kk);
    unsigned int lo = (unsigned)bfbits(v.x * sg) | ((unsigned)bfbits(v.y * sg) << 16);
    unsigned int hi = (unsigned)bfbits(v.z * sg) | ((unsigned)bfbits(v.w * sg) << 16);
    *(uint2*)(out + (size_t)idx * 4) = make_uint2(lo, hi);
  }
}

// ---------------------------------------------------------------- GEMM core (R3: BK=64 + swizzle)
// C[m,n] = sum_k A[m,k]*W[n,k]; A: Mx2048, W: Nx2048 bf16 row-major. 128x128 tile.
// LDS row = 64 elem (8 chunks of 16 B); LDS[r][c'] holds global chunk c'^(r&7).
__device__ __forceinline__ void gemm_core(const bf16_t* __restrict__ A,
                                          const bf16_t* __restrict__ W,
                                          int m0, int n0, f32x4 (&acc)[4][4]) {
  __shared__ __align__(16) bf16_t sA[128 * 64];
  __shared__ __align__(16) bf16_t sB[128 * 64];
  const int tid = threadIdx.x;
  const int lane = tid & 63, w = tid >> 6;
  const int wr = w >> 1, wc = w & 1;
  const int quad = lane >> 4, m16 = lane & 15;
  const int srow = w * 32 + (lane >> 3);                 // + i*8
  const int gcol = (((lane & 7) ^ (lane >> 3)) * 8);     // swizzled global k-offset
  const int swz7 = m16 & 7;                              // frag-read swizzle
  for (int k0 = 0; k0 < 2048; k0 += 64) {
    __syncthreads();
#pragma unroll
    for (int i = 0; i < 4; ++i) {
      gload_lds16(A + (size_t)(m0 + srow + i * 8) * 2048 + k0 + gcol,
                  sA + (size_t)(w * 32 + i * 8) * 64 + lane * 8);
      gload_lds16(W + (size_t)(n0 + srow + i * 8) * 2048 + k0 + gcol,
                  sB + (size_t)(w * 32 + i * 8) * 64 + lane * 8);
    }
    __syncthreads();
#pragma unroll
    for (int kk = 0; kk < 2; ++kk) {
      short8 af[4], bf[4];
#pragma unroll
      for (int i = 0; i < 4; ++i)
        af[i] = *(const short8*)(sA + (wr * 64 + i * 16 + m16) * 64 +
                                 ((kk * 4 + quad) ^ swz7) * 8);
#pragma unroll
      for (int j = 0; j < 4; ++j)
        bf[j] = *(const short8*)(sB + (wc * 64 + j * 16 + m16) * 64 +
                                 ((kk * 4 + quad) ^ swz7) * 8);
#pragma unroll
      for (int i = 0; i < 4; ++i)
#pragma unroll
        for (int j = 0; j < 4; ++j)
          acc[i][j] = __builtin_amdgcn_mfma_f32_16x16x32_bf16(af[i], bf[j], acc[i][j], 0, 0, 0);
    }
  }
}

// QKV GEMM: N=6144. cols 0..4095 -> qk [4096][4096] (Qr|Qi|Kr|Ki), Q pre-scaled by SCALE*log2e.
// cols 4096..6143 -> V transposed: vt[b*2048 + h*128 + ri*64 + d][seq]
__global__ __launch_bounds__(256) void gemm_qkv_k(const bf16_t* __restrict__ A,
                                                  const bf16_t* __restrict__ W,
                                                  bf16_t* __restrict__ qk,
                                                  bf16_t* __restrict__ vt) {
  f32x4 acc[4][4] = {};
  const int m0 = blockIdx.x * 128, n0 = blockIdx.y * 128;
  gemm_core(A, W, m0, n0, acc);
  const int lane = threadIdx.x & 63, w = threadIdx.x >> 6;
  const int wr = w >> 1, wc = w & 1, quad = lane >> 4, m16 = lane & 15;
#pragma unroll
  for (int i = 0; i < 4; ++i) {
    const int rowb = m0 + wr * 64 + i * 16 + quad * 4;  // C/D row = quad*4 + reg
#pragma unroll
    for (int j = 0; j < 4; ++j) {
      const int col = n0 + wc * 64 + j * 16 + m16;      // C/D col = lane&15
      if (col < 4096) {
        // 0.125 * log2(e): softmax later uses exp2
        const float sc = (col < 2048) ? 0.18033688f : 1.f;
#pragma unroll
        for (int r = 0; r < 4; ++r)
          qk[(size_t)(rowb + r) * 4096 + col] = __float2bfloat16(acc[i][j][r] * sc);
      } else {
        const int vcol = col - 4096;
        const int ri = vcol >> 10, dfeat = vcol & 1023;
        const int b = rowb >> 11, seq = rowb & 2047;
        const size_t vrow = (size_t)(b * 2048 + (dfeat >> 6) * 128 + ri * 64 + (dfeat & 63));
        unsigned int lo = (unsigned)bfbits(acc[i][j][0]) | ((unsigned)bfbits(acc[i][j][1]) << 16);
        unsigned int hi = (unsigned)bfbits(acc[i][j][2]) | ((unsigned)bfbits(acc[i][j][3]) << 16);
        *(uint2*)(vt + vrow * 2048 + seq) = make_uint2(lo, hi);
      }
    }
  }
}

// Output GEMM: N=2048 ([yr|yi]), fp32 out + bias.
__global__ __launch_bounds__(256) void gemm_out_k(const bf16_t* __restrict__ A,
                                                  const bf16_t* __restrict__ W,
                                                  const float* __restrict__ bor,
                                                  const float* __restrict__ boi,
                                                  float* __restrict__ out) {
  f32x4 acc[4][4] = {};
  const int m0 = blockIdx.x * 128, n0 = blockIdx.y * 128;
  gemm_core(A, W, m0, n0, acc);
  const int lane = threadIdx.x & 63, w = threadIdx.x >> 6;
  const int wr = w >> 1, wc = w & 1, quad = lane >> 4, m16 = lane & 15;
#pragma unroll
  for (int i = 0; i < 4; ++i) {
    const int rowb = m0 + wr * 64 + i * 16 + quad * 4;
#pragma unroll
    for (int j = 0; j < 4; ++j) {
      const int col = n0 + wc * 64 + j * 16 + m16;
      float bias; float* op;
      if (col < 1024) { bias = bor[col]; op = out + col; }
      else            { bias = boi[col - 1024]; op = out + 4194304 + (col - 1024); }
#pragma unroll
      for (int r = 0; r < 4; ++r)
        op[(size_t)(rowb + r) * 1024] = acc[i][j][r] + bias;
    }
  }
}

// ---------------------------------------------------------------- flash attention v7
// grid (32, B*H), 256 threads, 3 blocks/CU (LDS 41 KB). Block x pairs 32-row q-tiles
// x and 63-x. Each wave owns exactly ONE 16-row slice (no duplication):
//   w=0,1 -> rows x*32 + w*16        (tEnd = tDiag+1, short range)
//   w=2,3 -> rows (63-x)*32 + (w-2)*16 (tEnd = nT, full range)
// All waves stage all nT k-tiles (BK=64) via global_load_lds + XOR chunk swizzle; compute
// only t < tEnd. Fixed-max exp2 softmax (Q pre-scaled by SCALE*log2e); l via constant
// ones B-frag; diagonal mask provably needed only at t == tDiag (myq multiple of 16,
// myq >= 64*tDiag). Per-wave sP round-trip is lgkm-only.
__global__ __launch_bounds__(256, 3) void attn_k(const bf16_t* __restrict__ qk,
                                                 const bf16_t* __restrict__ vt,
                                                 bf16_t* __restrict__ acat) {
  __shared__ __align__(16) bf16_t sK[64 * 128];    // 16 KB
  __shared__ __align__(16) bf16_t sV[128 * 64];    // 16 KB
  __shared__ __align__(16) bf16_t sP[4][16 * 72];  // 9 KB (one part per wave)
  const int tid = threadIdx.x, lane = tid & 63, w = tid >> 6;
  const int quad = lane >> 4, m16 = lane & 15;
  const int x = blockIdx.x, bh = blockIdx.y, b = bh >> 4, h = bh & 15;
  const size_t qkrow0 = (size_t)b * 2048;
  const int myq = (w < 2) ? (x * 32 + w * 16) : ((63 - x) * 32 + (w - 2) * 16);
  const int tDiag = (myq + 15) >> 6;               // wave-uniform
  const int tEnd = tDiag + 1;
  const int nT = ((2047 - 32 * x) >> 6) + 1;       // block-uniform: 32 - ceil(x/2)
  const int swz7 = m16 & 7;

  // Q fragment (A-operand: m=lane&15, k=quad*8+j), d-chunks of 32 over Dc=128 (Qr|Qi)
  short8 qf[4];
  {
    const bf16_t* qa = qk + (qkrow0 + myq + m16) * 4096;
#pragma unroll
    for (int kk = 0; kk < 4; ++kk) {
      const int col = (kk >> 1) * 1024 + h * 64 + (kk & 1) * 32 + quad * 8;
      qf[kk] = *(const short8*)(qa + col);
    }
  }
  // constant ones B-frag: B[k][n]=1 iff n==0 -> PV col 0 = row-sum l
  short8 vones;
  {
    const short v = (m16 == 0) ? (short)0x3F80 : (short)0;
#pragma unroll
    for (int e = 0; e < 8; ++e) vones[e] = v;
  }
  f32x4 o[9];
#pragma unroll
  for (int j = 0; j < 9; ++j) o[j] = (f32x4){0.f, 0.f, 0.f, 0.f};

  const int qrow = myq + quad * 4;
  bf16_t* pw = &sP[w][0];

  // staging geometry (identical to R3/R6)
  const int kl4 = lane >> 4, kl15 = lane & 15;   // K tile: 4 rows/instr (256 B rows)
  const int vl3 = lane >> 3;                     // V tile: 8 rows/instr (128 B rows)
  const int vg7 = ((lane & 7) ^ vl3) * 8;

  for (int t = 0; t < nT; ++t) {
    const int k0 = t * 64;
    __syncthreads();
    // stage K: 64 rows x 128 elem (Kr|Ki of head h); row&7 = (i*4 + lane>>4)&7
#pragma unroll
    for (int i = 0; i < 4; ++i) {
      const int row = w * 16 + i * 4 + kl4;
      const int g = kl15 ^ (row & 7);            // low-3 XOR; bit3 of kl15 preserved
      const int col = 2048 + (g >> 3) * 1024 + h * 64 + (g & 7) * 8;
      gload_lds16(qk + (qkrow0 + k0 + row) * 4096 + col,
                  sK + (size_t)(w * 16 + i * 4) * 128 + lane * 8);
    }
    // stage V^T: 128 d-rows x 64 k; row&7 = lane>>3
#pragma unroll
    for (int i = 0; i < 4; ++i) {
      const int row = w * 32 + i * 8 + vl3;
      gload_lds16(vt + ((size_t)bh * 128 + row) * 2048 + k0 + vg7,
                  sV + (size_t)(w * 32 + i * 8) * 64 + lane * 8);
    }
    __syncthreads();

    if (t < tEnd) {
      const bool dg = (t == tDiag);

      // ---- S = Qs·K^T; exp2 fixed-max softmax into per-wave sP
#pragma unroll
      for (int jt = 0; jt < 4; ++jt) {
        short8 kf[4];
#pragma unroll
        for (int kk = 0; kk < 4; ++kk)
          kf[kk] = *(const short8*)(sK + (jt * 16 + m16) * 128 + ((kk * 4 + quad) ^ swz7) * 8);
        f32x4 a = (f32x4){0.f, 0.f, 0.f, 0.f};
#pragma unroll
        for (int kk = 0; kk < 4; ++kk)
          a = __builtin_amdgcn_mfma_f32_16x16x32_bf16(qf[kk], kf[kk], a, 0, 0, 0);
#pragma unroll
        for (int r = 0; r < 4; ++r) {
          float s = a[r];
          if (dg && (k0 + jt * 16 + m16 > qrow + r)) s = -1e30f;
          pw[(quad * 4 + r) * 72 + jt * 16 + m16] =
              __float2bfloat16(__builtin_amdgcn_exp2f(s));
        }
      }
      asm volatile("s_waitcnt lgkmcnt(0)" ::: "memory");  // own-wave P write->read

      // ---- O += P·V (j=8 = ones-frag -> l)
#pragma unroll
      for (int kc = 0; kc < 2; ++kc) {
        short8 p = *(const short8*)(pw + m16 * 72 + kc * 32 + quad * 8);
#pragma unroll
        for (int j = 0; j < 8; ++j) {
          short8 vf = *(const short8*)(sV + (j * 16 + m16) * 64 + ((kc * 4 + quad) ^ swz7) * 8);
          o[j] = __builtin_amdgcn_mfma_f32_16x16x32_bf16(p, vf, o[j], 0, 0, 0);
        }
        o[8] = __builtin_amdgcn_mfma_f32_16x16x32_bf16(p, vones, o[8], 0, 0, 0);
      }
    }
  }

  // ---- epilogue: l broadcast from lane (quad*16), normalize, write [B,L,2048]=[out_r|out_i]
  float inv[4];
#pragma unroll
  for (int r = 0; r < 4; ++r)
    inv[r] = 1.f / __shfl(o[8][r], lane & 48);
#pragma unroll
  for (int j = 0; j < 8; ++j) {
    const int d = j * 16 + m16;
    const int col = (d < 64) ? (h * 64 + d) : (1024 + h * 64 + (d - 64));
#pragma unroll
    for (int r = 0; r < 4; ++r)
      acat[((size_t)b * 2048 + qrow + r) * 2048 + col] = __float2bfloat16(o[j][r] * inv[r]);
  }
}

// ---------------------------------------------------------------- launch
extern "C" void kernel_launch(void* const* d_in, const int* in_sizes, int n_in,
                              void* d_out, int out_size, void* d_ws, size_t ws_size,
                              hipStream_t stream) {
  const float* xr  = (const float*)d_in[0];
  const float* xi  = (const float*)d_in[1];
  const float* wqr = (const float*)d_in[2];
  const float* wqi = (const float*)d_in[3];
  const float* wkr = (const float*)d_in[4];
  const float* wki = (const float*)d_in[5];
  const float* wvr = (const float*)d_in[6];
  const float* wvi = (const float*)d_in[7];
  const float* wor = (const float*)d_in[8];
  const float* woi = (const float*)d_in[9];
  const float* bor = (const float*)d_in[10];
  const float* boi = (const float*)d_in[11];
  float* out = (float*)d_out;

  char* ws = (char*)d_ws;
  bf16_t* Xcat = (bf16_t*)(ws);                   // 4096x2048   16 MB
  bf16_t* Wqkv = (bf16_t*)(ws + 16777216ull);     // 6144x2048   24 MB
  bf16_t* QKb  = (bf16_t*)(ws + 41943040ull);     // 4096x4096   32 MB
  bf16_t* Vt   = (bf16_t*)(ws + 75497472ull);     // 4096x2048   16 MB (V transposed)
  bf16_t* Acat = (bf16_t*)(ws + 92274688ull);     // 4096x2048   16 MB
  bf16_t* Wo   = (bf16_t*)(ws + 109051904ull);    // 2048x2048    8 MB

  pack_x_k<<<2048, 256, 0, stream>>>(xr, xi, Xcat);
  pack_wqkv_k<<<2048, 256, 0, stream>>>(wqr, wqi, wkr, wki, wvr, wvi, Wqkv);
  pack_wo_k<<<1024, 256, 0, stream>>>(wor, woi, Wo);
  gemm_qkv_k<<<dim3(32, 48), 256, 0, stream>>>(Xcat, Wqkv, QKb, Vt);
  attn_k<<<dim3(32, 32), 256, 0, stream>>>(QKb, Vt, Acat);
  gemm_out_k<<<dim3(32, 16), 256, 0, stream>>>(Acat, Wo, bor, boi, out);
}